// Round 3
// baseline (410.604 us; speedup 1.0000x reference)
//
#include <hip/hip_runtime.h>
#include <hip/hip_bf16.h>

#define NN 32768
#define NE 524288

typedef __attribute__((ext_vector_type(8))) short short8v;
typedef __attribute__((ext_vector_type(4))) float f32x4;

__device__ __forceinline__ float silu_f(float x){ return x * (1.0f/(1.0f+__expf(-x))); }
__device__ __forceinline__ float bf2f(unsigned short u){ return __uint_as_float(((unsigned)u)<<16); }
__device__ __forceinline__ unsigned short f2bf(float f){
  __hip_bfloat16 b = __float2bfloat16(f);
  return __builtin_bit_cast(unsigned short, b);
}
__device__ __forceinline__ unsigned pk2(float lo, float hi){
  return (unsigned)f2bf(lo) | ((unsigned)f2bf(hi) << 16);
}

#define S32 0.17677669529663687f   /* 1/sqrt(32) */
#define S8  0.35355339059327373f   /* 1/sqrt(8)  */
#define S64 0.125f                 /* 1/sqrt(64) */
#define R16 0.0625f                /* 1/16       */
#define NSC 0.08838834764831845f   /* 1/sqrt(128)*/
#define INV3F 0.5773502691896258f  /* 1/sqrt(3)  */

// ---------------- CSR build ----------------
__global__ void k_zero(int* __restrict__ deg){
  deg[blockIdx.x*256 + threadIdx.x] = 0;
}

__global__ void k_hist(const int* __restrict__ eidx, int* __restrict__ deg){
  int e = blockIdx.x*256 + threadIdx.x;
  int r = eidx[NE + e];           // receiver row of edge_index (2,E)
  atomicAdd(&deg[r], 1);
}

__global__ void __launch_bounds__(1024) k_scan(const int* __restrict__ deg,
    int* __restrict__ row_start, int* __restrict__ cursor){
  __shared__ int lds[1024];
  int t = threadIdx.x;
  int4 v[8];
  const int4* dg = reinterpret_cast<const int4*>(deg) + t*8;
  int s = 0;
  #pragma unroll
  for (int j=0;j<8;j++){ v[j] = dg[j]; s += v[j].x+v[j].y+v[j].z+v[j].w; }
  lds[t] = s; __syncthreads();
  for (int off=1; off<1024; off<<=1){
    int q = (t>=off)? lds[t-off] : 0; __syncthreads();
    lds[t] += q; __syncthreads();
  }
  int run = (t==0)?0:lds[t-1];
  int4* rs = reinterpret_cast<int4*>(row_start) + t*8;
  int4* cu = reinterpret_cast<int4*>(cursor) + t*8;
  #pragma unroll
  for (int j=0;j<8;j++){
    int4 o;
    o.x = run; run += v[j].x;
    o.y = run; run += v[j].y;
    o.z = run; run += v[j].z;
    o.w = run; run += v[j].w;
    rs[j] = o; cu[j] = o;
  }
  if (t==1023) row_start[NN] = run;
}

// csre[pos] = (edge, sender): kills one dependent load in k_recv
__global__ void k_scatter(const int* __restrict__ eidx, int* __restrict__ cursor,
                          int2* __restrict__ csre){
  int e = blockIdx.x*256 + threadIdx.x;
  int r = eidx[NE + e];
  int s = eidx[e];
  int pos = atomicAdd(&cursor[r], 1);
  csre[pos] = make_int2(e, s);
}

// ---------------- node pre-transform ----------------
// xtp row = 160 floats: [xs(32) | per u: (xv0,xv1,xv2,0) at 32+4u]
__global__ void k_xt(const float* __restrict__ nf, const float* __restrict__ W1s,
                     const float* __restrict__ W1v, float* __restrict__ xtp){
  int gid = blockIdx.x*256 + threadIdx.x;
  int n = gid / 160, c = gid % 160;
  const float* row = nf + (size_t)n*128;
  float acc = 0.f;
  if (c < 32){
    #pragma unroll
    for (int u=0;u<32;u++) acc += row[u] * W1s[u*32 + c];
  } else {
    int q = c - 32, v = q >> 2, i = q & 3;
    if (i < 3){
      #pragma unroll
      for (int u=0;u<32;u++) acc += row[32 + u*3 + i] * W1v[u*32 + v];
    }
  }
  xtp[(size_t)n*160 + c] = acc * S32;
}

// ---------------- weight fragment prep for MFMA MLP ----------------
// frag f, lane l: A-operand fragment; element j <-> k = 16*(j>=4) + (l>>4)*4 + (j&3)
__global__ void k_wprep(const float* __restrict__ Wf1, const float* __restrict__ Wf2,
                        const float* __restrict__ Wf3, short* __restrict__ wfrag){
  int f = blockIdx.x;
  int l = threadIdx.x;
  int c = l & 15, g = l >> 4;
  short8v pk;
  #pragma unroll
  for (int j=0;j<8;j++){
    int k = ((j&4) ? 16 : 0) + g*4 + (j&3);
    float val;
    if (f < 4){
      int m = f;
      val = (k < 8) ? Wf1[k*64 + m*16 + c] : 0.f;
    } else if (f < 12){
      int idx = f-4, m = idx>>1, kk = idx&1;
      val = Wf2[(kk*32+k)*64 + m*16 + c];
    } else {
      int idx = f-12, m = idx>>1, kk = idx&1;
      val = Wf3[(kk*32+k)*128 + m*16 + c];
    }
    pk[j] = (short)f2bf(val);
  }
  reinterpret_cast<short8v*>(wfrag)[f*64 + l] = pk;
}

// ---------------- edge MLP via MFMA, zero LDS ----------------
// D-fragment of layer i IS the B-fragment of layer i+1 (same lane, reg r <-> elem j):
// b[kk] = (silu-cvt of acc[2kk], acc[2kk+1]).
// Output packed for k_recv: wpair[e][64] dwords; lane' u<32: (w0[u], w1[u]);
// lane' 32+u: (w3[u]*INV3, w2[u]). All scaled by S64.
__global__ void __launch_bounds__(256) k_mlp2(const float* __restrict__ ef,
    const short* __restrict__ wfrag, unsigned* __restrict__ wpair){
  int lane = threadIdx.x & 63;
  int wv = threadIdx.x >> 6;
  int wid = blockIdx.x*4 + wv;
  int e_l = lane & 15, g = lane >> 4;

  short8v F[28];
  const short8v* wf = reinterpret_cast<const short8v*>(wfrag);
  #pragma unroll
  for (int f=0; f<28; f++) F[f] = wf[f*64 + lane];

  #pragma unroll 1
  for (int s=0; s<8; s++){
    int tile = wid + s*4096;
    // ---- layer 1 ----
    short8v bx = {};
    if (lane < 32){
      const float4 xv = *reinterpret_cast<const float4*>(
          ef + (size_t)(tile*16 + e_l)*8 + g*4);
      bx[0]=(short)f2bf(xv.x); bx[1]=(short)f2bf(xv.y);
      bx[2]=(short)f2bf(xv.z); bx[3]=(short)f2bf(xv.w);
    }
    f32x4 a1[4];
    #pragma unroll
    for (int m=0;m<4;m++){
      f32x4 z = {};
      a1[m] = __builtin_amdgcn_mfma_f32_16x16x32_bf16(F[m], bx, z, 0,0,0);
    }
    short8v b2[2];
    #pragma unroll
    for (int m=0;m<4;m++){
      #pragma unroll
      for (int r=0;r<4;r++)
        b2[m>>1][(m&1)*4 + r] = (short)f2bf(silu_f(a1[m][r]*S8));
    }
    // ---- layer 2 ----
    f32x4 a2[4] = {};
    #pragma unroll
    for (int kk=0;kk<2;kk++)
      #pragma unroll
      for (int m=0;m<4;m++)
        a2[m] = __builtin_amdgcn_mfma_f32_16x16x32_bf16(F[4+2*m+kk], b2[kk], a2[m], 0,0,0);
    short8v b3[2];
    #pragma unroll
    for (int m=0;m<4;m++){
      #pragma unroll
      for (int r=0;r<4;r++)
        b3[m>>1][(m&1)*4 + r] = (short)f2bf(silu_f(a2[m][r]*S64));
    }
    // ---- layer 3 ----
    f32x4 a3[8] = {};
    #pragma unroll
    for (int kk=0;kk<2;kk++)
      #pragma unroll
      for (int m=0;m<8;m++)
        a3[m] = __builtin_amdgcn_mfma_f32_16x16x32_bf16(F[12+2*m+kk], b3[kk], a3[m], 0,0,0);
    // ---- pack & store ----
    unsigned* dst = wpair + (size_t)(tile*16 + e_l)*64;
    #pragma unroll
    for (int mm=0; mm<2; mm++){
      uint4 o;  // (w0[u], w1[u]) : u = mm*16 + g*4 + r
      o.x = pk2(a3[mm][0]*S64, a3[mm+2][0]*S64);
      o.y = pk2(a3[mm][1]*S64, a3[mm+2][1]*S64);
      o.z = pk2(a3[mm][2]*S64, a3[mm+2][2]*S64);
      o.w = pk2(a3[mm][3]*S64, a3[mm+2][3]*S64);
      *reinterpret_cast<uint4*>(dst + mm*16 + g*4) = o;
    }
    #pragma unroll
    for (int mm=0; mm<2; mm++){
      uint4 o;  // (w3[u]*INV3, w2[u]) at 32 + mm*16 + g*4 + r
      o.x = pk2(a3[6+mm][0]*S64*INV3F, a3[4+mm][0]*S64);
      o.y = pk2(a3[6+mm][1]*S64*INV3F, a3[4+mm][1]*S64);
      o.z = pk2(a3[6+mm][2]*S64*INV3F, a3[4+mm][2]*S64);
      o.w = pk2(a3[6+mm][3]*S64*INV3F, a3[4+mm][3]*S64);
      *reinterpret_cast<uint4*>(dst + 32 + mm*16 + g*4) = o;
    }
  }
}

// ---------------- receiver: gather + aggregate + transforms + gate ----------------
__global__ void __launch_bounds__(256) k_recv(
    const float* __restrict__ nf, const float* __restrict__ na_g,
    const float* __restrict__ ea, const int* __restrict__ row_start,
    const int2* __restrict__ csre, const unsigned* __restrict__ wpair,
    const float* __restrict__ xtp,
    const float* __restrict__ W2s, const float* __restrict__ W2v,
    const float* __restrict__ Wsc_s, const float* __restrict__ Wsc_v,
    float* __restrict__ out){
  __shared__ float lds[4][320];
  int wv = threadIdx.x >> 6;
  int lane = threadIdx.x & 63;
  int n = blockIdx.x*4 + wv;
  float* L = lds[wv];
  int h1 = lane >> 5;
  int u = lane & 31;

  float a0=0.f, a1=0.f, a2=0.f, a3=0.f;

  auto edge = [&](int2 es){
    int e  = __builtin_amdgcn_readfirstlane(es.x);
    int sn = __builtin_amdgcn_readfirstlane(es.y);
    float4 sh = *reinterpret_cast<const float4*>(ea + (size_t)e*4);
    unsigned wp = wpair[(size_t)e*64 + lane];
    float wA = bf2f((unsigned short)(wp & 0xffffu));
    float wB = bf2f((unsigned short)(wp >> 16));
    float x0, x1, x2;
    if (h1){
      float4 q = *reinterpret_cast<const float4*>(xtp + (size_t)sn*160 + 32 + 4*u);
      x0=q.x; x1=q.y; x2=q.z;
    } else {
      x0 = xtp[(size_t)sn*160 + u]; x1 = x0; x2 = x0;
    }
    float c0 = h1 ? sh.y : sh.x;
    float c1 = h1 ? sh.z : 0.f;
    float c2 = h1 ? sh.w : 0.f;
    a0 += wA*(x0*c0 + x1*c1 + x2*c2);
    float g0 = wB*(h1 ? sh.x : sh.y);
    float g1 = wB*(h1 ? sh.x : sh.z);
    float g2 = wB*(h1 ? sh.x : sh.w);
    a1 += g0*x0; a2 += g1*x1; a3 += g2*x2;
  };

  int row = row_start[n], end = row_start[n+1];
  int idx = row;
  for (; idx+4 <= end; idx += 4){
    int2 e0 = csre[idx], e1 = csre[idx+1], e2 = csre[idx+2], e3 = csre[idx+3];
    edge(e0); edge(e1); edge(e2); edge(e3);
  }
  for (; idx < end; ++idx) edge(csre[idx]);

  // agg layout: [s(64) | v_i0(64) | v_i1(64) | v_i2(64)], scaled by 1/AVG_NEIGH
  L[lane]       = a0*R16;
  L[64  + lane] = a1*R16;
  L[128 + lane] = a2*R16;
  L[192 + lane] = a3*R16;
  __syncthreads();

  float na0 = na_g[(size_t)n*4+0], na1 = na_g[(size_t)n*4+1];
  float na2 = na_g[(size_t)n*4+2], na3 = na_g[(size_t)n*4+3];

  float os = 0.f;
  #pragma unroll 8
  for (int k=0;k<64;k++) os += L[k]*W2s[k*64+lane];
  os *= S64;
  float sk = 0.f;
  #pragma unroll 4
  for (int k=0;k<32;k++){
    float m = na0*Wsc_s[(k*4+0)*64+lane] + na1*Wsc_s[(k*4+1)*64+lane]
            + na2*Wsc_s[(k*4+2)*64+lane] + na3*Wsc_s[(k*4+3)*64+lane];
    sk += nf[(size_t)n*128+k]*m;
  }
  os += sk*NSC;
  float sil = silu_f(os);
  L[256+lane] = sil;   // lanes 32..63 hold gates
  __syncthreads();

  if (lane < 32){
    float ov0=0.f, ov1=0.f, ov2=0.f;
    #pragma unroll 8
    for (int k=0;k<64;k++){
      float w = W2v[k*32+lane];
      ov0 += L[64+k]*w; ov1 += L[128+k]*w; ov2 += L[192+k]*w;
    }
    ov0 *= S64; ov1 *= S64; ov2 *= S64;
    float s0=0.f, s1=0.f, s2=0.f;
    #pragma unroll 4
    for (int k=0;k<32;k++){
      float m = na0*Wsc_v[(k*4+0)*32+lane] + na1*Wsc_v[(k*4+1)*32+lane]
              + na2*Wsc_v[(k*4+2)*32+lane] + na3*Wsc_v[(k*4+3)*32+lane];
      s0 += nf[(size_t)n*128 + 32 + k*3 + 0]*m;
      s1 += nf[(size_t)n*128 + 32 + k*3 + 1]*m;
      s2 += nf[(size_t)n*128 + 32 + k*3 + 2]*m;
    }
    ov0 += s0*NSC; ov1 += s1*NSC; ov2 += s2*NSC;
    float gate = L[256+32+lane];
    size_t b = (size_t)n*128;
    out[b+lane] = nf[b+lane] + sil;
    out[b+32+lane*3+0] = nf[b+32+lane*3+0] + ov0*gate;
    out[b+32+lane*3+1] = nf[b+32+lane*3+1] + ov1*gate;
    out[b+32+lane*3+2] = nf[b+32+lane*3+2] + ov2*gate;
  }
}

extern "C" void kernel_launch(void* const* d_in, const int* in_sizes, int n_in,
                              void* d_out, int out_size, void* d_ws, size_t ws_size,
                              hipStream_t stream) {
  const float* nf    = (const float*)d_in[0];
  const float* na    = (const float*)d_in[1];
  const float* ef    = (const float*)d_in[2];
  const float* ea    = (const float*)d_in[3];
  const float* W1s   = (const float*)d_in[4];
  const float* W1v   = (const float*)d_in[5];
  const float* Wf1   = (const float*)d_in[6];
  const float* Wf2   = (const float*)d_in[7];
  const float* Wf3   = (const float*)d_in[8];
  const float* W2s   = (const float*)d_in[9];
  const float* W2v   = (const float*)d_in[10];
  const float* Wsc_s = (const float*)d_in[11];
  const float* Wsc_v = (const float*)d_in[12];
  const int*   eidx  = (const int*)d_in[13];
  float* out = (float*)d_out;

  char* ws = (char*)d_ws;
  size_t off = 0;
  auto alloc = [&](size_t bytes)->void*{
    void* p = ws + off; off += (bytes + 255) & ~(size_t)255; return p;
  };
  float*    xtp       = (float*)alloc((size_t)NN*160*4);
  unsigned* wpair     = (unsigned*)alloc((size_t)NE*64*4);
  int*      deg       = (int*)alloc((size_t)NN*4);
  int*      row_start = (int*)alloc((size_t)(NN+16)*4);
  int*      cursor    = (int*)alloc((size_t)NN*4);
  int2*     csre      = (int2*)alloc((size_t)NE*8);
  short*    wfrag     = (short*)alloc((size_t)28*64*8*2);
  if (off > ws_size) return;  // insufficient scratch — fail visibly

  k_zero   <<<NN/256, 256, 0, stream>>>(deg);
  k_hist   <<<NE/256, 256, 0, stream>>>(eidx, deg);
  k_scan   <<<1, 1024, 0, stream>>>(deg, row_start, cursor);
  k_scatter<<<NE/256, 256, 0, stream>>>(eidx, cursor, csre);
  k_xt     <<<(NN*160)/256, 256, 0, stream>>>(nf, W1s, W1v, xtp);
  k_wprep  <<<28, 64, 0, stream>>>(Wf1, Wf2, Wf3, wfrag);
  k_mlp2   <<<1024, 256, 0, stream>>>(ef, wfrag, wpair);
  k_recv   <<<NN/4, 256, 0, stream>>>(nf, na, ea, row_start, csre,
                                      wpair, xtp, W2s, W2v, Wsc_s, Wsc_v, out);
}

// Round 4
// 340.966 us; speedup vs baseline: 1.2042x; 1.2042x over previous
//
#include <hip/hip_runtime.h>
#include <hip/hip_bf16.h>

#define NN 32768
#define NE 524288

typedef __attribute__((ext_vector_type(8))) short short8v;
typedef __attribute__((ext_vector_type(4))) short short4v;
typedef __attribute__((ext_vector_type(4))) float f32x4;

__device__ __forceinline__ float silu_f(float x){ return x * (1.0f/(1.0f+__expf(-x))); }
__device__ __forceinline__ float bf2f(unsigned short u){ return __uint_as_float(((unsigned)u)<<16); }
__device__ __forceinline__ unsigned short f2bf(float f){
  __hip_bfloat16 b = __float2bfloat16(f);
  return __builtin_bit_cast(unsigned short, b);
}
__device__ __forceinline__ unsigned pk2(float lo, float hi){
  return (unsigned)f2bf(lo) | ((unsigned)f2bf(hi) << 16);
}

#define S32 0.17677669529663687f   /* 1/sqrt(32) */
#define S8  0.35355339059327373f   /* 1/sqrt(8)  */
#define S64 0.125f                 /* 1/sqrt(64) */
#define R16 0.0625f                /* 1/16       */
#define NSC 0.08838834764831845f   /* 1/sqrt(128)*/
#define INV3F 0.5773502691896258f  /* 1/sqrt(3)  */

// ---------------- CSR build ----------------
__global__ void k_zero(int* __restrict__ deg){
  deg[blockIdx.x*256 + threadIdx.x] = 0;
}

__global__ void k_hist(const int* __restrict__ eidx, int* __restrict__ deg){
  int e = blockIdx.x*256 + threadIdx.x;
  int r = eidx[NE + e];
  atomicAdd(&deg[r], 1);
}

__global__ void __launch_bounds__(1024) k_scan(const int* __restrict__ deg,
    int* __restrict__ row_start, int* __restrict__ cursor){
  __shared__ int lds[1024];
  int t = threadIdx.x;
  int4 v[8];
  const int4* dg = reinterpret_cast<const int4*>(deg) + t*8;
  int s = 0;
  #pragma unroll
  for (int j=0;j<8;j++){ v[j] = dg[j]; s += v[j].x+v[j].y+v[j].z+v[j].w; }
  lds[t] = s; __syncthreads();
  for (int off=1; off<1024; off<<=1){
    int q = (t>=off)? lds[t-off] : 0; __syncthreads();
    lds[t] += q; __syncthreads();
  }
  int run = (t==0)?0:lds[t-1];
  int4* rs = reinterpret_cast<int4*>(row_start) + t*8;
  int4* cu = reinterpret_cast<int4*>(cursor) + t*8;
  #pragma unroll
  for (int j=0;j<8;j++){
    int4 o;
    o.x = run; run += v[j].x;
    o.y = run; run += v[j].y;
    o.z = run; run += v[j].z;
    o.w = run; run += v[j].w;
    rs[j] = o; cu[j] = o;
  }
  if (t==1023) row_start[NN] = run;
}

__global__ void k_scatter(const int* __restrict__ eidx, int* __restrict__ cursor,
                          int2* __restrict__ csre){
  int e = blockIdx.x*256 + threadIdx.x;
  int r = eidx[NE + e];
  int s = eidx[e];
  int pos = atomicAdd(&cursor[r], 1);
  csre[pos] = make_int2(e, s);
}

// ---------------- node pre-transform ----------------
// xtp2[n][u*4 + {0:xs, 1:xv0, 2:xv1, 3:xv2}] — one float4 per u.
__global__ void k_xt(const float* __restrict__ nf, const float* __restrict__ W1s,
                     const float* __restrict__ W1v, float* __restrict__ xtp2){
  int gid = blockIdx.x*256 + threadIdx.x;
  int n = gid >> 7, c = gid & 127, u = c >> 2, comp = c & 3;
  const float* src = nf + (size_t)n*128 + (comp==0 ? 0 : 32 + (comp-1));
  int stride = (comp==0) ? 1 : 3;
  const float* W = (comp==0) ? W1s : W1v;
  float acc = 0.f;
  #pragma unroll
  for (int t=0;t<32;t++) acc += src[t*stride] * W[t*32 + u];
  xtp2[gid] = acc * S32;
}

// ---------------- weight fragment prep ----------------
// A-frag convention (validated R2/R3): lane l: c=l&15, g=l>>4,
// elem j: k = kbase + 16*(j>=4) + g*4 + (j&3); val = M[k][m*16+c].
// blocks 0..27: MLP frags (Wf1/Wf2/Wf3) -> wfrag
// blocks 28..63: epi frags -> wfe: f'=kb*6+p; p<4: s-path (192x64), p>=4: v-path (192x32)
__global__ void k_wprep(const float* __restrict__ Wf1, const float* __restrict__ Wf2,
                        const float* __restrict__ Wf3,
                        const float* __restrict__ W2s, const float* __restrict__ W2v,
                        const float* __restrict__ Wsc_s, const float* __restrict__ Wsc_v,
                        short* __restrict__ wfrag, short* __restrict__ wfe){
  int f = blockIdx.x;
  int l = threadIdx.x;
  int c = l & 15, g = l >> 4;
  short8v pk;
  if (f < 28){
    #pragma unroll
    for (int j=0;j<8;j++){
      int k = ((j&4) ? 16 : 0) + g*4 + (j&3);
      float val;
      if (f < 4){
        int m = f;
        val = (k < 8) ? Wf1[k*64 + m*16 + c] : 0.f;
      } else if (f < 12){
        int idx = f-4, m = idx>>1, kk = idx&1;
        val = Wf2[(kk*32+k)*64 + m*16 + c];
      } else {
        int idx = f-12, m = idx>>1, kk = idx&1;
        val = Wf3[(kk*32+k)*128 + m*16 + c];
      }
      pk[j] = (short)f2bf(val);
    }
    reinterpret_cast<short8v*>(wfrag)[f*64 + l] = pk;
  } else {
    int fe = f - 28, kb = fe/6, p = fe%6;
    #pragma unroll
    for (int j=0;j<8;j++){
      int k = kb*32 + ((j&4) ? 16 : 0) + g*4 + (j&3);
      float val;
      if (p < 4){
        int col = p*16 + c;
        val = (k < 64) ? W2s[k*64 + col]*S64 : Wsc_s[(k-64)*64 + col]*NSC;
      } else {
        int col = (p-4)*16 + c;
        val = (k < 64) ? W2v[k*32 + col]*S64 : Wsc_v[(k-64)*32 + col]*NSC;
      }
      pk[j] = (short)f2bf(val);
    }
    reinterpret_cast<short8v*>(wfe)[fe*64 + l] = pk;
  }
}

// ---------------- edge MLP via MFMA ----------------
// wpair[e][64] dwords; u<32: (w0[u], w1[u]); 32+u: (w3[u]*INV3, w2[u]); all *S64.
// Stores staged through LDS -> fully coalesced 4KB/tile.
__global__ void __launch_bounds__(256) k_mlp2(const float* __restrict__ ef,
    const short* __restrict__ wfrag, unsigned* __restrict__ wpair){
  __shared__ unsigned sb[4][16][68];
  int lane = threadIdx.x & 63;
  int wv = threadIdx.x >> 6;
  int wid = blockIdx.x*4 + wv;
  int e_l = lane & 15, g = lane >> 4;
  const short8v* wf = reinterpret_cast<const short8v*>(wfrag);

  #pragma unroll 1
  for (int s=0; s<2; s++){
    int tile = wid*2 + s;
    // ---- layer 1 ----
    short8v bx = {};
    if (lane < 32){
      const float4 xv = *reinterpret_cast<const float4*>(
          ef + (size_t)(tile*16 + e_l)*8 + g*4);
      bx[0]=(short)f2bf(xv.x); bx[1]=(short)f2bf(xv.y);
      bx[2]=(short)f2bf(xv.z); bx[3]=(short)f2bf(xv.w);
    }
    f32x4 a1[4];
    #pragma unroll
    for (int m=0;m<4;m++){
      f32x4 z = {};
      a1[m] = __builtin_amdgcn_mfma_f32_16x16x32_bf16(wf[m*64+lane], bx, z, 0,0,0);
    }
    short8v b2[2];
    #pragma unroll
    for (int m=0;m<4;m++)
      #pragma unroll
      for (int r=0;r<4;r++)
        b2[m>>1][(m&1)*4 + r] = (short)f2bf(silu_f(a1[m][r]*S8));
    // ---- layer 2 ----
    f32x4 a2[4] = {};
    #pragma unroll
    for (int kk=0;kk<2;kk++)
      #pragma unroll
      for (int m=0;m<4;m++)
        a2[m] = __builtin_amdgcn_mfma_f32_16x16x32_bf16(wf[(4+2*m+kk)*64+lane], b2[kk], a2[m], 0,0,0);
    short8v b3[2];
    #pragma unroll
    for (int m=0;m<4;m++)
      #pragma unroll
      for (int r=0;r<4;r++)
        b3[m>>1][(m&1)*4 + r] = (short)f2bf(silu_f(a2[m][r]*S64));
    // ---- layer 3 ----
    f32x4 a3[8] = {};
    #pragma unroll
    for (int kk=0;kk<2;kk++)
      #pragma unroll
      for (int m=0;m<8;m++)
        a3[m] = __builtin_amdgcn_mfma_f32_16x16x32_bf16(wf[(12+2*m+kk)*64+lane], b3[kk], a3[m], 0,0,0);
    // ---- pack into LDS ----
    #pragma unroll
    for (int mm=0; mm<2; mm++){
      uint4 o;
      o.x = pk2(a3[mm][0]*S64, a3[mm+2][0]*S64);
      o.y = pk2(a3[mm][1]*S64, a3[mm+2][1]*S64);
      o.z = pk2(a3[mm][2]*S64, a3[mm+2][2]*S64);
      o.w = pk2(a3[mm][3]*S64, a3[mm+2][3]*S64);
      *reinterpret_cast<uint4*>(&sb[wv][e_l][mm*16 + g*4]) = o;
      uint4 o2;
      o2.x = pk2(a3[6+mm][0]*S64*INV3F, a3[4+mm][0]*S64);
      o2.y = pk2(a3[6+mm][1]*S64*INV3F, a3[4+mm][1]*S64);
      o2.z = pk2(a3[6+mm][2]*S64*INV3F, a3[4+mm][2]*S64);
      o2.w = pk2(a3[6+mm][3]*S64*INV3F, a3[4+mm][3]*S64);
      *reinterpret_cast<uint4*>(&sb[wv][e_l][32 + mm*16 + g*4]) = o2;
    }
    __syncthreads();
    // ---- coalesced store: wave covers contiguous 4KB ----
    unsigned* gd = wpair + (size_t)tile*1024;
    #pragma unroll
    for (int q=0;q<4;q++){
      uint4 v = *reinterpret_cast<uint4*>(&sb[wv][lane>>2][(lane&3)*16 + q*4]);
      *reinterpret_cast<uint4*>(gd + lane*16 + q*4) = v;
    }
    __syncthreads();
  }
}

// ---------------- receiver: pure gather + aggregate, 2 waves/node ----------------
__global__ void __launch_bounds__(256) k_recv(
    const float* __restrict__ ea, const int* __restrict__ row_start,
    const int2* __restrict__ csre, const unsigned* __restrict__ wpair,
    const float* __restrict__ xtp2, unsigned* __restrict__ agg){
  __shared__ float L[4][256];
  int wb = threadIdx.x >> 6;
  int lane = threadIdx.x & 63;
  int nl = wb >> 1, w = wb & 1;
  int n = blockIdx.x*2 + nl;
  int u = lane & 31;
  bool h1 = lane >= 32;

  int row = row_start[n], end = row_start[n+1];
  int mid = (row + end + 1) >> 1;
  int lo = w ? mid : row;
  int hi = w ? end : mid;

  float a0=0.f, a1=0.f, a2=0.f, a3=0.f;

  auto body = [&](int2 es){
    int e  = __builtin_amdgcn_readfirstlane(es.x);
    int sn = __builtin_amdgcn_readfirstlane(es.y);
    float4 sh = *reinterpret_cast<const float4*>(ea + (size_t)e*4);
    unsigned wp = wpair[(size_t)e*64 + lane];
    float4 q = *reinterpret_cast<const float4*>(xtp2 + (size_t)sn*128 + u*4);
    float wA = bf2f((unsigned short)(wp & 0xffffu));
    float wB = bf2f((unsigned short)(wp >> 16));
    float x0 = h1 ? q.y : q.x;
    float x1 = h1 ? q.z : q.x;
    float x2 = h1 ? q.w : q.x;
    float c0 = h1 ? sh.y : sh.x;
    float c1 = h1 ? sh.z : 0.f;
    float c2 = h1 ? sh.w : 0.f;
    a0 += wA*(x0*c0 + x1*c1 + x2*c2);
    float g0 = wB*(h1 ? sh.x : sh.y);
    float g1 = wB*(h1 ? sh.x : sh.z);
    float g2 = wB*(h1 ? sh.x : sh.w);
    a1 += g0*x0; a2 += g1*x1; a3 += g2*x2;
  };

  int idx = lo;
  for (; idx+4 <= hi; idx += 4){
    int2 e0 = csre[idx], e1 = csre[idx+1], e2 = csre[idx+2], e3 = csre[idx+3];
    body(e0); body(e1); body(e2); body(e3);
  }
  for (; idx < hi; ++idx) body(csre[idx]);

  float* P = L[wb];
  P[lane] = a0; P[64+lane] = a1; P[128+lane] = a2; P[192+lane] = a3;
  __syncthreads();

  int t = threadIdx.x;
  int nl2 = t >> 7, cp = t & 127;
  float v0 = (L[nl2*2][2*cp  ] + L[nl2*2+1][2*cp  ]) * R16;
  float v1 = (L[nl2*2][2*cp+1] + L[nl2*2+1][2*cp+1]) * R16;
  agg[(size_t)(blockIdx.x*2 + nl2)*128 + cp] = pk2(v0, v1);
}

// ---------------- epilogue GEMM: [agg|kron] @ [W2;Wsc] + silu/gate/residual ----------------
__global__ void __launch_bounds__(256) k_epi(
    const float* __restrict__ nf, const float* __restrict__ na,
    const unsigned short* __restrict__ agg, const short* __restrict__ wfe,
    float* __restrict__ out){
  __shared__ float L[4][16][168];
  int wv = threadIdx.x >> 6, lane = threadIdx.x & 63;
  int tile = blockIdx.x*4 + wv;
  int e = lane & 15, g = lane >> 4;
  int n = tile*16 + e;
  const short8v* WE = reinterpret_cast<const short8v*>(wfe);
  const unsigned short* ag = agg + (size_t)n*256;
  const float* nfr = nf + (size_t)n*128;
  float4 nav = *reinterpret_cast<const float4*>(na + (size_t)n*4);

  f32x4 as0={},as1={},as2={},as3={};
  f32x4 av00={},av01={},av10={},av11={},av20={},av21={};

  #pragma unroll
  for (int kb=0; kb<6; kb++){
    short8v bs, bv0, bv1, bv2;
    if (kb < 2){
      int k0 = kb*32 + g*4;
      #pragma unroll
      for (int i=0;i<4;i++){
        short4v qa = *reinterpret_cast<const short4v*>(ag + i*64 + k0);
        short4v qb = *reinterpret_cast<const short4v*>(ag + i*64 + k0 + 16);
        short8v b;
        b[0]=qa[0]; b[1]=qa[1]; b[2]=qa[2]; b[3]=qa[3];
        b[4]=qb[0]; b[5]=qb[1]; b[6]=qb[2]; b[7]=qb[3];
        if (i==0) bs = b; else if (i==1) bv0 = b; else if (i==2) bv1 = b; else bv2 = b;
      }
    } else {
      int u0 = (kb-2)*8 + g;
      float x0 = nfr[u0], x1 = nfr[u0+4];
      bs[0]=(short)f2bf(x0*nav.x); bs[1]=(short)f2bf(x0*nav.y);
      bs[2]=(short)f2bf(x0*nav.z); bs[3]=(short)f2bf(x0*nav.w);
      bs[4]=(short)f2bf(x1*nav.x); bs[5]=(short)f2bf(x1*nav.y);
      bs[6]=(short)f2bf(x1*nav.z); bs[7]=(short)f2bf(x1*nav.w);
      #pragma unroll
      for (int i=0;i<3;i++){
        float y0 = nfr[32 + u0*3 + i], y1 = nfr[32 + (u0+4)*3 + i];
        short8v b;
        b[0]=(short)f2bf(y0*nav.x); b[1]=(short)f2bf(y0*nav.y);
        b[2]=(short)f2bf(y0*nav.z); b[3]=(short)f2bf(y0*nav.w);
        b[4]=(short)f2bf(y1*nav.x); b[5]=(short)f2bf(y1*nav.y);
        b[6]=(short)f2bf(y1*nav.z); b[7]=(short)f2bf(y1*nav.w);
        if (i==0) bv0 = b; else if (i==1) bv1 = b; else bv2 = b;
      }
    }
    as0 = __builtin_amdgcn_mfma_f32_16x16x32_bf16(WE[(kb*6+0)*64+lane], bs, as0, 0,0,0);
    as1 = __builtin_amdgcn_mfma_f32_16x16x32_bf16(WE[(kb*6+1)*64+lane], bs, as1, 0,0,0);
    as2 = __builtin_amdgcn_mfma_f32_16x16x32_bf16(WE[(kb*6+2)*64+lane], bs, as2, 0,0,0);
    as3 = __builtin_amdgcn_mfma_f32_16x16x32_bf16(WE[(kb*6+3)*64+lane], bs, as3, 0,0,0);
    av00 = __builtin_amdgcn_mfma_f32_16x16x32_bf16(WE[(kb*6+4)*64+lane], bv0, av00, 0,0,0);
    av01 = __builtin_amdgcn_mfma_f32_16x16x32_bf16(WE[(kb*6+5)*64+lane], bv0, av01, 0,0,0);
    av10 = __builtin_amdgcn_mfma_f32_16x16x32_bf16(WE[(kb*6+4)*64+lane], bv1, av10, 0,0,0);
    av11 = __builtin_amdgcn_mfma_f32_16x16x32_bf16(WE[(kb*6+5)*64+lane], bv1, av11, 0,0,0);
    av20 = __builtin_amdgcn_mfma_f32_16x16x32_bf16(WE[(kb*6+4)*64+lane], bv2, av20, 0,0,0);
    av21 = __builtin_amdgcn_mfma_f32_16x16x32_bf16(WE[(kb*6+5)*64+lane], bv2, av21, 0,0,0);
  }

  // stash to LDS: rows 0..63 = silu(out_s) (scalars + gates); 64+q = out_v (q = v*3+i)
  float (*Lw)[168] = L[wv];
  #pragma unroll
  for (int r=0;r<4;r++){
    Lw[e][ 0 + g*4 + r] = silu_f(as0[r]);
    Lw[e][16 + g*4 + r] = silu_f(as1[r]);
    Lw[e][32 + g*4 + r] = silu_f(as2[r]);
    Lw[e][48 + g*4 + r] = silu_f(as3[r]);
    Lw[e][64 + (     g*4 + r)*3 + 0] = av00[r];
    Lw[e][64 + (16 + g*4 + r)*3 + 0] = av01[r];
    Lw[e][64 + (     g*4 + r)*3 + 1] = av10[r];
    Lw[e][64 + (16 + g*4 + r)*3 + 1] = av11[r];
    Lw[e][64 + (     g*4 + r)*3 + 2] = av20[r];
    Lw[e][64 + (16 + g*4 + r)*3 + 2] = av21[r];
  }
  __syncthreads();

  if (g == 0){
    #pragma unroll
    for (int c=0;c<32;c+=4){
      float4 nv = *reinterpret_cast<const float4*>(nfr + c);
      float4 o;
      o.x = nv.x + Lw[e][c  ];
      o.y = nv.y + Lw[e][c+1];
      o.z = nv.z + Lw[e][c+2];
      o.w = nv.w + Lw[e][c+3];
      *reinterpret_cast<float4*>(out + (size_t)n*128 + c) = o;
    }
  } else {
    int q0 = (g-1)*32;
    #pragma unroll
    for (int q=q0; q<q0+32; q+=4){
      float4 nv = *reinterpret_cast<const float4*>(nfr + 32 + q);
      float4 o;
      o.x = nv.x + Lw[e][64+q+0]*Lw[e][32+(q+0)/3];
      o.y = nv.y + Lw[e][64+q+1]*Lw[e][32+(q+1)/3];
      o.z = nv.z + Lw[e][64+q+2]*Lw[e][32+(q+2)/3];
      o.w = nv.w + Lw[e][64+q+3]*Lw[e][32+(q+3)/3];
      *reinterpret_cast<float4*>(out + (size_t)n*128 + 32 + q) = o;
    }
  }
}

extern "C" void kernel_launch(void* const* d_in, const int* in_sizes, int n_in,
                              void* d_out, int out_size, void* d_ws, size_t ws_size,
                              hipStream_t stream) {
  const float* nf    = (const float*)d_in[0];
  const float* na    = (const float*)d_in[1];
  const float* ef    = (const float*)d_in[2];
  const float* ea    = (const float*)d_in[3];
  const float* W1s   = (const float*)d_in[4];
  const float* W1v   = (const float*)d_in[5];
  const float* Wf1   = (const float*)d_in[6];
  const float* Wf2   = (const float*)d_in[7];
  const float* Wf3   = (const float*)d_in[8];
  const float* W2s   = (const float*)d_in[9];
  const float* W2v   = (const float*)d_in[10];
  const float* Wsc_s = (const float*)d_in[11];
  const float* Wsc_v = (const float*)d_in[12];
  const int*   eidx  = (const int*)d_in[13];
  float* out = (float*)d_out;

  char* ws = (char*)d_ws;
  size_t off = 0;
  auto alloc = [&](size_t bytes)->void*{
    void* p = ws + off; off += (bytes + 255) & ~(size_t)255; return p;
  };
  float*    xtp2      = (float*)alloc((size_t)NN*128*4);
  unsigned* wpair     = (unsigned*)alloc((size_t)NE*64*4);
  unsigned* agg       = (unsigned*)alloc((size_t)NN*256*2);
  int*      deg       = (int*)alloc((size_t)NN*4);
  int*      row_start = (int*)alloc((size_t)(NN+16)*4);
  int*      cursor    = (int*)alloc((size_t)NN*4);
  int2*     csre      = (int2*)alloc((size_t)NE*8);
  short*    wfrag     = (short*)alloc((size_t)28*64*8*2);
  short*    wfe       = (short*)alloc((size_t)36*64*8*2);
  if (off > ws_size) return;  // insufficient scratch — fail visibly

  k_zero   <<<NN/256, 256, 0, stream>>>(deg);
  k_hist   <<<NE/256, 256, 0, stream>>>(eidx, deg);
  k_scan   <<<1, 1024, 0, stream>>>(deg, row_start, cursor);
  k_scatter<<<NE/256, 256, 0, stream>>>(eidx, cursor, csre);
  k_xt     <<<(NN*128)/256, 256, 0, stream>>>(nf, W1s, W1v, xtp2);
  k_wprep  <<<64, 64, 0, stream>>>(Wf1, Wf2, Wf3, W2s, W2v, Wsc_s, Wsc_v, wfrag, wfe);
  k_mlp2   <<<4096, 256, 0, stream>>>(ef, wfrag, wpair);
  k_recv   <<<NN/2, 256, 0, stream>>>(ea, row_start, csre, wpair, xtp2,
                                      (unsigned*)agg);
  k_epi    <<<512, 256, 0, stream>>>(nf, na, (const unsigned short*)agg, wfe, out);
}

// Round 5
// 247.894 us; speedup vs baseline: 1.6564x; 1.3754x over previous
//
#include <hip/hip_runtime.h>
#include <hip/hip_bf16.h>

#define NN 32768
#define NE 524288

typedef __attribute__((ext_vector_type(8))) short short8v;
typedef __attribute__((ext_vector_type(4))) short short4v;
typedef __attribute__((ext_vector_type(4))) float f32x4;

__device__ __forceinline__ float silu_f(float x){ return x * (1.0f/(1.0f+__expf(-x))); }
__device__ __forceinline__ float bf2f(unsigned short u){ return __uint_as_float(((unsigned)u)<<16); }
__device__ __forceinline__ unsigned short f2bf(float f){
  __hip_bfloat16 b = __float2bfloat16(f);
  return __builtin_bit_cast(unsigned short, b);
}
__device__ __forceinline__ unsigned pk2(float lo, float hi){
  return (unsigned)f2bf(lo) | ((unsigned)f2bf(hi) << 16);
}

#define S32 0.17677669529663687f   /* 1/sqrt(32) */
#define S8  0.35355339059327373f   /* 1/sqrt(8)  */
#define S64 0.125f                 /* 1/sqrt(64) */
#define R16 0.0625f                /* 1/16       */
#define NSC 0.08838834764831845f   /* 1/sqrt(128)*/
#define INV3F 0.5773502691896258f  /* 1/sqrt(3)  */

// ---------------- CSR build ----------------
__global__ void k_zero(int* __restrict__ deg){
  deg[blockIdx.x*256 + threadIdx.x] = 0;
}

__global__ void k_hist(const int* __restrict__ eidx, int* __restrict__ deg){
  int e = blockIdx.x*256 + threadIdx.x;
  int r = eidx[NE + e];
  atomicAdd(&deg[r], 1);
}

__global__ void __launch_bounds__(1024) k_scan(const int* __restrict__ deg,
    int* __restrict__ row_start, int* __restrict__ cursor){
  __shared__ int lds[1024];
  int t = threadIdx.x;
  int4 v[8];
  const int4* dg = reinterpret_cast<const int4*>(deg) + t*8;
  int s = 0;
  #pragma unroll
  for (int j=0;j<8;j++){ v[j] = dg[j]; s += v[j].x+v[j].y+v[j].z+v[j].w; }
  lds[t] = s; __syncthreads();
  for (int off=1; off<1024; off<<=1){
    int q = (t>=off)? lds[t-off] : 0; __syncthreads();
    lds[t] += q; __syncthreads();
  }
  int run = (t==0)?0:lds[t-1];
  int4* rs = reinterpret_cast<int4*>(row_start) + t*8;
  int4* cu = reinterpret_cast<int4*>(cursor) + t*8;
  #pragma unroll
  for (int j=0;j<8;j++){
    int4 o;
    o.x = run; run += v[j].x;
    o.y = run; run += v[j].y;
    o.z = run; run += v[j].z;
    o.w = run; run += v[j].w;
    rs[j] = o; cu[j] = o;
  }
  if (t==1023) row_start[NN] = run;
}

__global__ void k_scatter(const int* __restrict__ eidx, int* __restrict__ cursor,
                          int2* __restrict__ csre){
  int e = blockIdx.x*256 + threadIdx.x;
  int r = eidx[NE + e];
  int s = eidx[e];
  int pos = atomicAdd(&cursor[r], 1);
  csre[pos] = make_int2(e, s);
}

// ---------------- node pre-transform ----------------
// xtp2[n][u*4 + {0:xs, 1:xv0, 2:xv1, 3:xv2}] — one float4 per u.
// W column hoisted to registers (invariant per thread); node rows staged in LDS.
#define XT_ITERS 16
__global__ void __launch_bounds__(256) k_xt(const float* __restrict__ nf,
    const float* __restrict__ W1s, const float* __restrict__ W1v,
    float* __restrict__ xtp2){
  __shared__ float rowbuf[256];
  int t = threadIdx.x;
  int c = t & 127, u = c >> 2, comp = c & 3;
  int node = t >> 7;
  const float* W = (comp==0) ? W1s : W1v;
  float wreg[32];
  #pragma unroll
  for (int k=0;k<32;k++) wreg[k] = W[k*32 + u];
  int soff = node*128 + (comp==0 ? 0 : 32 + (comp-1));
  int stride = (comp==0) ? 1 : 3;
  int base = blockIdx.x * (2*XT_ITERS);
  #pragma unroll 1
  for (int it=0; it<XT_ITERS; it++){
    int n0 = base + it*2;
    __syncthreads();
    rowbuf[t] = nf[(size_t)n0*128 + t];
    __syncthreads();
    float acc = 0.f;
    #pragma unroll
    for (int k=0;k<32;k++) acc += rowbuf[soff + k*stride] * wreg[k];
    xtp2[(size_t)(n0+node)*128 + c] = acc * S32;
  }
}

// ---------------- weight fragment prep ----------------
// A-frag convention (validated R2/R3): lane l: c=l&15, g=l>>4,
// elem j: k = kbase + 16*(j>=4) + g*4 + (j&3); val = M[k][m*16+c].
// blocks 0..27: MLP frags (Wf1/Wf2/Wf3) -> wfrag
// blocks 28..63: epi frags -> wfe: f'=kb*6+p; p<4: s-path (192x64), p>=4: v-path (192x32)
__global__ void k_wprep(const float* __restrict__ Wf1, const float* __restrict__ Wf2,
                        const float* __restrict__ Wf3,
                        const float* __restrict__ W2s, const float* __restrict__ W2v,
                        const float* __restrict__ Wsc_s, const float* __restrict__ Wsc_v,
                        short* __restrict__ wfrag, short* __restrict__ wfe){
  int f = blockIdx.x;
  int l = threadIdx.x;
  int c = l & 15, g = l >> 4;
  short8v pk;
  if (f < 28){
    #pragma unroll
    for (int j=0;j<8;j++){
      int k = ((j&4) ? 16 : 0) + g*4 + (j&3);
      float val;
      if (f < 4){
        int m = f;
        val = (k < 8) ? Wf1[k*64 + m*16 + c] : 0.f;
      } else if (f < 12){
        int idx = f-4, m = idx>>1, kk = idx&1;
        val = Wf2[(kk*32+k)*64 + m*16 + c];
      } else {
        int idx = f-12, m = idx>>1, kk = idx&1;
        val = Wf3[(kk*32+k)*128 + m*16 + c];
      }
      pk[j] = (short)f2bf(val);
    }
    reinterpret_cast<short8v*>(wfrag)[f*64 + l] = pk;
  } else {
    int fe = f - 28, kb = fe/6, p = fe%6;
    #pragma unroll
    for (int j=0;j<8;j++){
      int k = kb*32 + ((j&4) ? 16 : 0) + g*4 + (j&3);
      float val;
      if (p < 4){
        int col = p*16 + c;
        val = (k < 64) ? W2s[k*64 + col]*S64 : Wsc_s[(k-64)*64 + col]*NSC;
      } else {
        int col = (p-4)*16 + c;
        val = (k < 64) ? W2v[k*32 + col]*S64 : Wsc_v[(k-64)*32 + col]*NSC;
      }
      pk[j] = (short)f2bf(val);
    }
    reinterpret_cast<short8v*>(wfe)[fe*64 + l] = pk;
  }
}

// ---------------- edge MLP via MFMA ----------------
// wpair[e][64] dwords; u<32: (w0[u], w1[u]); 32+u: (w3[u]*INV3, w2[u]); all *S64.
// Stores staged through LDS -> fully coalesced 4KB/tile.
__global__ void __launch_bounds__(256) k_mlp2(const float* __restrict__ ef,
    const short* __restrict__ wfrag, unsigned* __restrict__ wpair){
  __shared__ unsigned sb[4][16][68];
  int lane = threadIdx.x & 63;
  int wv = threadIdx.x >> 6;
  int wid = blockIdx.x*4 + wv;
  int e_l = lane & 15, g = lane >> 4;
  const short8v* wf = reinterpret_cast<const short8v*>(wfrag);

  #pragma unroll 1
  for (int s=0; s<2; s++){
    int tile = wid*2 + s;
    // ---- layer 1 ----
    short8v bx = {};
    if (lane < 32){
      const float4 xv = *reinterpret_cast<const float4*>(
          ef + (size_t)(tile*16 + e_l)*8 + g*4);
      bx[0]=(short)f2bf(xv.x); bx[1]=(short)f2bf(xv.y);
      bx[2]=(short)f2bf(xv.z); bx[3]=(short)f2bf(xv.w);
    }
    f32x4 a1[4];
    #pragma unroll
    for (int m=0;m<4;m++){
      f32x4 z = {};
      a1[m] = __builtin_amdgcn_mfma_f32_16x16x32_bf16(wf[m*64+lane], bx, z, 0,0,0);
    }
    short8v b2[2];
    #pragma unroll
    for (int m=0;m<4;m++)
      #pragma unroll
      for (int r=0;r<4;r++)
        b2[m>>1][(m&1)*4 + r] = (short)f2bf(silu_f(a1[m][r]*S8));
    // ---- layer 2 ----
    f32x4 a2[4] = {};
    #pragma unroll
    for (int kk=0;kk<2;kk++)
      #pragma unroll
      for (int m=0;m<4;m++)
        a2[m] = __builtin_amdgcn_mfma_f32_16x16x32_bf16(wf[(4+2*m+kk)*64+lane], b2[kk], a2[m], 0,0,0);
    short8v b3[2];
    #pragma unroll
    for (int m=0;m<4;m++)
      #pragma unroll
      for (int r=0;r<4;r++)
        b3[m>>1][(m&1)*4 + r] = (short)f2bf(silu_f(a2[m][r]*S64));
    // ---- layer 3 ----
    f32x4 a3[8] = {};
    #pragma unroll
    for (int kk=0;kk<2;kk++)
      #pragma unroll
      for (int m=0;m<8;m++)
        a3[m] = __builtin_amdgcn_mfma_f32_16x16x32_bf16(wf[(12+2*m+kk)*64+lane], b3[kk], a3[m], 0,0,0);
    // ---- pack into LDS ----
    #pragma unroll
    for (int mm=0; mm<2; mm++){
      uint4 o;
      o.x = pk2(a3[mm][0]*S64, a3[mm+2][0]*S64);
      o.y = pk2(a3[mm][1]*S64, a3[mm+2][1]*S64);
      o.z = pk2(a3[mm][2]*S64, a3[mm+2][2]*S64);
      o.w = pk2(a3[mm][3]*S64, a3[mm+2][3]*S64);
      *reinterpret_cast<uint4*>(&sb[wv][e_l][mm*16 + g*4]) = o;
      uint4 o2;
      o2.x = pk2(a3[6+mm][0]*S64*INV3F, a3[4+mm][0]*S64);
      o2.y = pk2(a3[6+mm][1]*S64*INV3F, a3[4+mm][1]*S64);
      o2.z = pk2(a3[6+mm][2]*S64*INV3F, a3[4+mm][2]*S64);
      o2.w = pk2(a3[6+mm][3]*S64*INV3F, a3[4+mm][3]*S64);
      *reinterpret_cast<uint4*>(&sb[wv][e_l][32 + mm*16 + g*4]) = o2;
    }
    __syncthreads();
    // ---- coalesced store: wave covers contiguous 4KB ----
    unsigned* gd = wpair + (size_t)tile*1024;
    #pragma unroll
    for (int q=0;q<4;q++){
      uint4 v = *reinterpret_cast<uint4*>(&sb[wv][lane>>2][(lane&3)*16 + q*4]);
      *reinterpret_cast<uint4*>(gd + lane*16 + q*4) = v;
    }
    __syncthreads();
  }
}

// ---------------- receiver: pure gather + aggregate, 2 waves/node ----------------
__global__ void __launch_bounds__(256) k_recv(
    const float* __restrict__ ea, const int* __restrict__ row_start,
    const int2* __restrict__ csre, const unsigned* __restrict__ wpair,
    const float* __restrict__ xtp2, unsigned* __restrict__ agg){
  __shared__ float L[4][256];
  int wb = threadIdx.x >> 6;
  int lane = threadIdx.x & 63;
  int nl = wb >> 1, w = wb & 1;
  int n = blockIdx.x*2 + nl;
  int u = lane & 31;
  bool h1 = lane >= 32;

  int row = row_start[n], end = row_start[n+1];
  int mid = (row + end + 1) >> 1;
  int lo = w ? mid : row;
  int hi = w ? end : mid;

  float a0=0.f, a1=0.f, a2=0.f, a3=0.f;

  auto body = [&](int2 es){
    int e  = __builtin_amdgcn_readfirstlane(es.x);
    int sn = __builtin_amdgcn_readfirstlane(es.y);
    float4 sh = *reinterpret_cast<const float4*>(ea + (size_t)e*4);
    unsigned wp = wpair[(size_t)e*64 + lane];
    float4 q = *reinterpret_cast<const float4*>(xtp2 + (size_t)sn*128 + u*4);
    float wA = bf2f((unsigned short)(wp & 0xffffu));
    float wB = bf2f((unsigned short)(wp >> 16));
    float x0 = h1 ? q.y : q.x;
    float x1 = h1 ? q.z : q.x;
    float x2 = h1 ? q.w : q.x;
    float c0 = h1 ? sh.y : sh.x;
    float c1 = h1 ? sh.z : 0.f;
    float c2 = h1 ? sh.w : 0.f;
    a0 += wA*(x0*c0 + x1*c1 + x2*c2);
    float g0 = wB*(h1 ? sh.x : sh.y);
    float g1 = wB*(h1 ? sh.x : sh.z);
    float g2 = wB*(h1 ? sh.x : sh.w);
    a1 += g0*x0; a2 += g1*x1; a3 += g2*x2;
  };

  int idx = lo;
  for (; idx+4 <= hi; idx += 4){
    int2 e0 = csre[idx], e1 = csre[idx+1], e2 = csre[idx+2], e3 = csre[idx+3];
    body(e0); body(e1); body(e2); body(e3);
  }
  for (; idx < hi; ++idx) body(csre[idx]);

  float* P = L[wb];
  P[lane] = a0; P[64+lane] = a1; P[128+lane] = a2; P[192+lane] = a3;
  __syncthreads();

  int t = threadIdx.x;
  int nl2 = t >> 7, cp = t & 127;
  float v0 = (L[nl2*2][2*cp  ] + L[nl2*2+1][2*cp  ]) * R16;
  float v1 = (L[nl2*2][2*cp+1] + L[nl2*2+1][2*cp+1]) * R16;
  agg[(size_t)(blockIdx.x*2 + nl2)*128 + cp] = pk2(v0, v1);
}

// ---------------- epilogue GEMM: [agg|kron] @ [W2;Wsc] + silu/gate/residual ----------------
__global__ void __launch_bounds__(256) k_epi(
    const float* __restrict__ nf, const float* __restrict__ na,
    const unsigned short* __restrict__ agg, const short* __restrict__ wfe,
    float* __restrict__ out){
  __shared__ float L[4][16][168];
  int wv = threadIdx.x >> 6, lane = threadIdx.x & 63;
  int tile = blockIdx.x*4 + wv;
  int e = lane & 15, g = lane >> 4;
  int n = tile*16 + e;
  const short8v* WE = reinterpret_cast<const short8v*>(wfe);
  const unsigned short* ag = agg + (size_t)n*256;
  const float* nfr = nf + (size_t)n*128;
  float4 nav = *reinterpret_cast<const float4*>(na + (size_t)n*4);

  f32x4 as0={},as1={},as2={},as3={};
  f32x4 av00={},av01={},av10={},av11={},av20={},av21={};

  #pragma unroll
  for (int kb=0; kb<6; kb++){
    short8v bs, bv0, bv1, bv2;
    if (kb < 2){
      int k0 = kb*32 + g*4;
      #pragma unroll
      for (int i=0;i<4;i++){
        short4v qa = *reinterpret_cast<const short4v*>(ag + i*64 + k0);
        short4v qb = *reinterpret_cast<const short4v*>(ag + i*64 + k0 + 16);
        short8v b;
        b[0]=qa[0]; b[1]=qa[1]; b[2]=qa[2]; b[3]=qa[3];
        b[4]=qb[0]; b[5]=qb[1]; b[6]=qb[2]; b[7]=qb[3];
        if (i==0) bs = b; else if (i==1) bv0 = b; else if (i==2) bv1 = b; else bv2 = b;
      }
    } else {
      int u0 = (kb-2)*8 + g;
      float x0 = nfr[u0], x1 = nfr[u0+4];
      bs[0]=(short)f2bf(x0*nav.x); bs[1]=(short)f2bf(x0*nav.y);
      bs[2]=(short)f2bf(x0*nav.z); bs[3]=(short)f2bf(x0*nav.w);
      bs[4]=(short)f2bf(x1*nav.x); bs[5]=(short)f2bf(x1*nav.y);
      bs[6]=(short)f2bf(x1*nav.z); bs[7]=(short)f2bf(x1*nav.w);
      #pragma unroll
      for (int i=0;i<3;i++){
        float y0 = nfr[32 + u0*3 + i], y1 = nfr[32 + (u0+4)*3 + i];
        short8v b;
        b[0]=(short)f2bf(y0*nav.x); b[1]=(short)f2bf(y0*nav.y);
        b[2]=(short)f2bf(y0*nav.z); b[3]=(short)f2bf(y0*nav.w);
        b[4]=(short)f2bf(y1*nav.x); b[5]=(short)f2bf(y1*nav.y);
        b[6]=(short)f2bf(y1*nav.z); b[7]=(short)f2bf(y1*nav.w);
        if (i==0) bv0 = b; else if (i==1) bv1 = b; else bv2 = b;
      }
    }
    as0 = __builtin_amdgcn_mfma_f32_16x16x32_bf16(WE[(kb*6+0)*64+lane], bs, as0, 0,0,0);
    as1 = __builtin_amdgcn_mfma_f32_16x16x32_bf16(WE[(kb*6+1)*64+lane], bs, as1, 0,0,0);
    as2 = __builtin_amdgcn_mfma_f32_16x16x32_bf16(WE[(kb*6+2)*64+lane], bs, as2, 0,0,0);
    as3 = __builtin_amdgcn_mfma_f32_16x16x32_bf16(WE[(kb*6+3)*64+lane], bs, as3, 0,0,0);
    av00 = __builtin_amdgcn_mfma_f32_16x16x32_bf16(WE[(kb*6+4)*64+lane], bv0, av00, 0,0,0);
    av01 = __builtin_amdgcn_mfma_f32_16x16x32_bf16(WE[(kb*6+5)*64+lane], bv0, av01, 0,0,0);
    av10 = __builtin_amdgcn_mfma_f32_16x16x32_bf16(WE[(kb*6+4)*64+lane], bv1, av10, 0,0,0);
    av11 = __builtin_amdgcn_mfma_f32_16x16x32_bf16(WE[(kb*6+5)*64+lane], bv1, av11, 0,0,0);
    av20 = __builtin_amdgcn_mfma_f32_16x16x32_bf16(WE[(kb*6+4)*64+lane], bv2, av20, 0,0,0);
    av21 = __builtin_amdgcn_mfma_f32_16x16x32_bf16(WE[(kb*6+5)*64+lane], bv2, av21, 0,0,0);
  }

  // stash to LDS: rows 0..63 = silu(out_s) (scalars + gates); 64+q = out_v (q = v*3+i)
  float (*Lw)[168] = L[wv];
  #pragma unroll
  for (int r=0;r<4;r++){
    Lw[e][ 0 + g*4 + r] = silu_f(as0[r]);
    Lw[e][16 + g*4 + r] = silu_f(as1[r]);
    Lw[e][32 + g*4 + r] = silu_f(as2[r]);
    Lw[e][48 + g*4 + r] = silu_f(as3[r]);
    Lw[e][64 + (     g*4 + r)*3 + 0] = av00[r];
    Lw[e][64 + (16 + g*4 + r)*3 + 0] = av01[r];
    Lw[e][64 + (     g*4 + r)*3 + 1] = av10[r];
    Lw[e][64 + (16 + g*4 + r)*3 + 1] = av11[r];
    Lw[e][64 + (     g*4 + r)*3 + 2] = av20[r];
    Lw[e][64 + (16 + g*4 + r)*3 + 2] = av21[r];
  }
  __syncthreads();

  if (g == 0){
    #pragma unroll
    for (int c=0;c<32;c+=4){
      float4 nv = *reinterpret_cast<const float4*>(nfr + c);
      float4 o;
      o.x = nv.x + Lw[e][c  ];
      o.y = nv.y + Lw[e][c+1];
      o.z = nv.z + Lw[e][c+2];
      o.w = nv.w + Lw[e][c+3];
      *reinterpret_cast<float4*>(out + (size_t)n*128 + c) = o;
    }
  } else {
    int q0 = (g-1)*32;
    #pragma unroll
    for (int q=q0; q<q0+32; q+=4){
      float4 nv = *reinterpret_cast<const float4*>(nfr + 32 + q);
      float4 o;
      o.x = nv.x + Lw[e][64+q+0]*Lw[e][32+(q+0)/3];
      o.y = nv.y + Lw[e][64+q+1]*Lw[e][32+(q+1)/3];
      o.z = nv.z + Lw[e][64+q+2]*Lw[e][32+(q+2)/3];
      o.w = nv.w + Lw[e][64+q+3]*Lw[e][32+(q+3)/3];
      *reinterpret_cast<float4*>(out + (size_t)n*128 + 32 + q) = o;
    }
  }
}

extern "C" void kernel_launch(void* const* d_in, const int* in_sizes, int n_in,
                              void* d_out, int out_size, void* d_ws, size_t ws_size,
                              hipStream_t stream) {
  const float* nf    = (const float*)d_in[0];
  const float* na    = (const float*)d_in[1];
  const float* ef    = (const float*)d_in[2];
  const float* ea    = (const float*)d_in[3];
  const float* W1s   = (const float*)d_in[4];
  const float* W1v   = (const float*)d_in[5];
  const float* Wf1   = (const float*)d_in[6];
  const float* Wf2   = (const float*)d_in[7];
  const float* Wf3   = (const float*)d_in[8];
  const float* W2s   = (const float*)d_in[9];
  const float* W2v   = (const float*)d_in[10];
  const float* Wsc_s = (const float*)d_in[11];
  const float* Wsc_v = (const float*)d_in[12];
  const int*   eidx  = (const int*)d_in[13];
  float* out = (float*)d_out;

  char* ws = (char*)d_ws;
  size_t off = 0;
  auto alloc = [&](size_t bytes)->void*{
    void* p = ws + off; off += (bytes + 255) & ~(size_t)255; return p;
  };
  float*    xtp2      = (float*)alloc((size_t)NN*128*4);
  unsigned* wpair     = (unsigned*)alloc((size_t)NE*64*4);
  unsigned* agg       = (unsigned*)alloc((size_t)NN*256*2);
  int*      deg       = (int*)alloc((size_t)NN*4);
  int*      row_start = (int*)alloc((size_t)(NN+16)*4);
  int*      cursor    = (int*)alloc((size_t)NN*4);
  int2*     csre      = (int2*)alloc((size_t)NE*8);
  short*    wfrag     = (short*)alloc((size_t)28*64*8*2);
  short*    wfe       = (short*)alloc((size_t)36*64*8*2);
  if (off > ws_size) return;  // insufficient scratch — fail visibly

  k_zero   <<<NN/256, 256, 0, stream>>>(deg);
  k_hist   <<<NE/256, 256, 0, stream>>>(eidx, deg);
  k_scan   <<<1, 1024, 0, stream>>>(deg, row_start, cursor);
  k_scatter<<<NE/256, 256, 0, stream>>>(eidx, cursor, csre);
  k_xt     <<<NN/(2*XT_ITERS), 256, 0, stream>>>(nf, W1s, W1v, xtp2);
  k_wprep  <<<64, 64, 0, stream>>>(Wf1, Wf2, Wf3, W2s, W2v, Wsc_s, Wsc_v, wfrag, wfe);
  k_mlp2   <<<4096, 256, 0, stream>>>(ef, wfrag, wpair);
  k_recv   <<<NN/2, 256, 0, stream>>>(ea, row_start, csre, wpair, xtp2,
                                      (unsigned*)agg);
  k_epi    <<<512, 256, 0, stream>>>(nf, na, (const unsigned short*)agg, wfe, out);
}